// Round 9
// baseline (410.636 us; speedup 1.0000x reference)
//
#include <hip/hip_runtime.h>
#include <math.h>

// CRF forward-score scan, faithful to the reference's quirky log_sum_exp.
// Base-2 factorization (HW-verified r5/r6/r8, absmax 0.0):
//   M2_i   = max_j(fv2_j + tr2_ij)
//   h_j    = exp2(fv2_j - M2_j - feat2_j)
//   fv2'_i = M2_i + 2*feat2_i + log2(sum_j exp(tr_ij) * h_j)
//
// Measured ladder: r5 3-wave+2barriers = 832 cyc/step; r6 KSEQ=4x3-wave
// (redundant LDS) = 2038; r8 1-wave no-barrier = 975 (zero latency hiding:
// the full chain of 2 LDS round-trips + trees + exp/log + unhidden issue).
// r9: TWO independent sequences per wave (64 blocks x 64 thr). Chain B's
// issue fills chain A's stalls in the same wave; DS ops stay linear (no r6
// redundancy), counted lgkmcnt waits let both round-trips pipeline.
// Expected ~800 cyc per 2-seq step -> ~90-110 us.
//
// Per-seq layout (= r8): lane = i16*4+jsub; jsub owns j in [12jsub,12jsub+12);
// rows i16, i16+16, i16+32 per lane (16x4x3 = 48 rows x 4-lane quads).
// Wave-synchronous LDS (in-order DS pipe, no barriers). Features via
// global_load_lds, double-buffered 32-step chunks, vmcnt(0) at sl==30.

#define TT 48
#define BB 128
#define SS 512
#define STARTI 46
#define ENDI 47
#define MINV 0.0001f
#define KSEQ 2
#define NBLK (BB / KSEQ)      // 64
#define CHUNK 32
#define NCHUNK (SS / CHUNK)   // 16
#define GPT 6                 // gload16 per chunk per seq: 32*48*4B/(64*16B)
#define LOG2E 1.44269504088896340736f
#define LN2   0.69314718055994530942f

#if __has_builtin(__builtin_amdgcn_exp2f)
#define EXP2F(x) __builtin_amdgcn_exp2f(x)
#else
#define EXP2F(x) exp2f(x)
#endif
#if __has_builtin(__builtin_amdgcn_logf)   // v_log_f32: log base 2
#define LOG2F(x) __builtin_amdgcn_logf(x)
#else
#define LOG2F(x) log2f(x)
#endif

// quad_perm DPP: cross-lane within each aligned 4-lane group, VALU pipe.
// 0xB1 = [1,0,3,2] (xor 1), 0x4E = [2,3,0,1] (xor 2).
template <int CTRL>
__device__ __forceinline__ float qperm_f(float x) {
#if __has_builtin(__builtin_amdgcn_update_dpp)
    return __int_as_float(__builtin_amdgcn_update_dpp(
        0, __float_as_int(x), CTRL, 0xF, 0xF, true));
#elif __has_builtin(__builtin_amdgcn_mov_dpp)
    return __int_as_float(
        __builtin_amdgcn_mov_dpp(__float_as_int(x), CTRL, 0xF, 0xF, true));
#else
    return __shfl_xor(x, (CTRL == 0xB1) ? 1 : 2, 64);
#endif
}

#if __has_builtin(__builtin_amdgcn_global_load_lds)
#define HAVE_GLOAD 1
__device__ __forceinline__ void gload16(const float* g, float* l) {
    __builtin_amdgcn_global_load_lds(
        (const __attribute__((address_space(1))) void*)g,
        (__attribute__((address_space(3))) void*)l, 16, 0, 0);
}
#else
#define HAVE_GLOAD 0
#endif

__global__ __launch_bounds__(64, 1) void crf_forward_kernel(
    const float* __restrict__ feats,   // [B, S, T]
    const float* __restrict__ trans,   // [T, T]
    float* __restrict__ out)           // [B]
{
    const int lane = threadIdx.x;      // 0..63
    const int i16  = lane >> 2;        // 0..15
    const int jsub = lane & 3;         // 0..3
    const int j0   = jsub * 12;
    const int b0   = blockIdx.x * KSEQ;

    __shared__ __align__(16) float fvb[KSEQ][TT];
    __shared__ __align__(16) float hb[KSEQ][TT];
    __shared__ __align__(16) float featbuf[KSEQ][2][CHUNK * TT];  // 2x2x6KB

    // Per-lane slices for rows i16+16r (shared by both seqs).
    float tr2[3][12], E[3][12];
#pragma unroll
    for (int r = 0; r < 3; ++r) {
#pragma unroll
        for (int q = 0; q < 3; ++q) {
            float4 v = *reinterpret_cast<const float4*>(
                trans + (i16 + 16 * r) * TT + j0 + 4 * q);
            tr2[r][4 * q + 0] = v.x * LOG2E; tr2[r][4 * q + 1] = v.y * LOG2E;
            tr2[r][4 * q + 2] = v.z * LOG2E; tr2[r][4 * q + 3] = v.w * LOG2E;
        }
#pragma unroll
        for (int q = 0; q < 12; ++q) E[r][q] = EXP2F(tr2[r][q]);
    }

    const float* fbs[KSEQ];
#pragma unroll
    for (int s = 0; s < KSEQ; ++s)
        fbs[s] = feats + (size_t)(b0 + s) * SS * TT;

    // Preload chunk 0 for both seqs.
#pragma unroll
    for (int s = 0; s < KSEQ; ++s) {
#if HAVE_GLOAD
#pragma unroll
        for (int k = 0; k < GPT; ++k)
            gload16(fbs[s] + k * 256 + lane * 4, &featbuf[s][0][k * 256]);
#else
#pragma unroll
        for (int k = 0; k < GPT; ++k)
            *reinterpret_cast<float4*>(&featbuf[s][0][k * 256 + lane * 4]) =
                *reinterpret_cast<const float4*>(fbs[s] + k * 256 + lane * 4);
#endif
    }

    if (lane < TT) {
#pragma unroll
        for (int s = 0; s < KSEQ; ++s)
            fvb[s][lane] = (lane == STARTI) ? 0.0f : (MINV * LOG2E);
    }
    float fvi[KSEQ][3];
#pragma unroll
    for (int s = 0; s < KSEQ; ++s)
#pragma unroll
        for (int r = 0; r < 3; ++r)
            fvi[s][r] = ((i16 + 16 * r) == STARTI) ? 0.0f : (MINV * LOG2E);

#if HAVE_GLOAD
    asm volatile("s_waitcnt vmcnt(0)" ::: "memory");
#endif

    for (int c = 0; c < NCHUNK; ++c) {
        const int buf = c & 1;
        const bool hp = (c + 1 < NCHUNK);
        if (hp) {
#pragma unroll
            for (int s = 0; s < KSEQ; ++s) {
#if HAVE_GLOAD
#pragma unroll
                for (int k = 0; k < GPT; ++k)
                    gload16(fbs[s] + (c + 1) * (CHUNK * TT) + k * 256 + lane * 4,
                            &featbuf[s][buf ^ 1][k * 256]);
#else
#pragma unroll
                for (int k = 0; k < GPT; ++k)
                    *reinterpret_cast<float4*>(
                        &featbuf[s][buf ^ 1][k * 256 + lane * 4]) =
                        *reinterpret_cast<const float4*>(
                            fbs[s] + (c + 1) * (CHUNK * TT) + k * 256 + lane * 4);
#endif
            }
        }

        for (int sl = 0; sl < CHUNK; ++sl) {
            // Issue both seqs' feat + fv reads first; chains interleave below.
            float feat2[KSEQ][3];
#pragma unroll
            for (int s = 0; s < KSEQ; ++s)
#pragma unroll
                for (int r = 0; r < 3; ++r)
                    feat2[s][r] =
                        featbuf[s][buf][sl * TT + i16 + 16 * r] * LOG2E;

            float fvs[KSEQ][12];
#pragma unroll
            for (int s = 0; s < KSEQ; ++s) {
                float4 v0 = *reinterpret_cast<const float4*>(&fvb[s][j0]);
                float4 v1 = *reinterpret_cast<const float4*>(&fvb[s][j0 + 4]);
                float4 v2 = *reinterpret_cast<const float4*>(&fvb[s][j0 + 8]);
                fvs[s][0] = v0.x; fvs[s][1] = v0.y; fvs[s][2]  = v0.z; fvs[s][3]  = v0.w;
                fvs[s][4] = v1.x; fvs[s][5] = v1.y; fvs[s][6]  = v1.z; fvs[s][7]  = v1.w;
                fvs[s][8] = v2.x; fvs[s][9] = v2.y; fvs[s][10] = v2.z; fvs[s][11] = v2.w;
            }

            float hs[KSEQ][3], qv2[KSEQ][3];
#pragma unroll
            for (int s = 0; s < KSEQ; ++s) {
#pragma unroll
                for (int r = 0; r < 3; ++r) {
                    float a[12];
#pragma unroll
                    for (int q = 0; q < 12; ++q) a[q] = fvs[s][q] + tr2[r][q];
                    float m0 = fmaxf(fmaxf(a[0], a[1]),  a[2]);
                    float m1 = fmaxf(fmaxf(a[3], a[4]),  a[5]);
                    float m2 = fmaxf(fmaxf(a[6], a[7]),  a[8]);
                    float m3 = fmaxf(fmaxf(a[9], a[10]), a[11]);
                    float M2 = fmaxf(fmaxf(fmaxf(m0, m1), m2), m3);
                    M2 = fmaxf(M2, qperm_f<0xB1>(M2));
                    M2 = fmaxf(M2, qperm_f<0x4E>(M2));
                    hs[s][r]  = EXP2F((fvi[s][r] - feat2[s][r]) - M2);
                    qv2[s][r] = M2 + 2.0f * feat2[s][r];
                }
            }
            if (jsub == 0) {
#pragma unroll
                for (int s = 0; s < KSEQ; ++s) {
                    hb[s][i16]      = hs[s][0];
                    hb[s][i16 + 16] = hs[s][1];
                    hb[s][i16 + 32] = hs[s][2];
                }
            }
            // Wave-synchronous: in-order DS pipe; counted lgkm waits let both
            // seqs' round-trips pipeline.
            float hv[KSEQ][12];
#pragma unroll
            for (int s = 0; s < KSEQ; ++s) {
                float4 h0 = *reinterpret_cast<const float4*>(&hb[s][j0]);
                float4 h1 = *reinterpret_cast<const float4*>(&hb[s][j0 + 4]);
                float4 h2 = *reinterpret_cast<const float4*>(&hb[s][j0 + 8]);
                hv[s][0] = h0.x; hv[s][1] = h0.y; hv[s][2]  = h0.z; hv[s][3]  = h0.w;
                hv[s][4] = h1.x; hv[s][5] = h1.y; hv[s][6]  = h1.z; hv[s][7]  = h1.w;
                hv[s][8] = h2.x; hv[s][9] = h2.y; hv[s][10] = h2.z; hv[s][11] = h2.w;
            }

            float nfv[KSEQ][3];
#pragma unroll
            for (int s = 0; s < KSEQ; ++s) {
#pragma unroll
                for (int r = 0; r < 3; ++r) {
                    float d0 = E[r][0] * hv[s][0], d1 = E[r][1] * hv[s][1];
                    float d2 = E[r][2] * hv[s][2], d3 = E[r][3] * hv[s][3];
                    d0 = fmaf(E[r][4],  hv[s][4],  d0);
                    d1 = fmaf(E[r][5],  hv[s][5],  d1);
                    d2 = fmaf(E[r][6],  hv[s][6],  d2);
                    d3 = fmaf(E[r][7],  hv[s][7],  d3);
                    d0 = fmaf(E[r][8],  hv[s][8],  d0);
                    d1 = fmaf(E[r][9],  hv[s][9],  d1);
                    d2 = fmaf(E[r][10], hv[s][10], d2);
                    d3 = fmaf(E[r][11], hv[s][11], d3);
                    float dot = (d0 + d1) + (d2 + d3);
                    dot += qperm_f<0xB1>(dot);
                    dot += qperm_f<0x4E>(dot);
                    nfv[s][r] = qv2[s][r] + LOG2F(dot);
                    fvi[s][r] = nfv[s][r];
                }
            }
            if (jsub == 0) {
#pragma unroll
                for (int s = 0; s < KSEQ; ++s) {
                    fvb[s][i16]      = nfv[s][0];
                    fvb[s][i16 + 16] = nfv[s][1];
                    fvb[s][i16 + 32] = nfv[s][2];
                }
            }
#if HAVE_GLOAD
            if (sl == CHUNK - 2 && hp)
                asm volatile("s_waitcnt vmcnt(0)" ::: "memory");
#endif
        }
    }

    // ---- terminal per seq: out = LSE_j( fv_j + trans[END][j] ) ----
    {
        const float* te = trans + ENDI * TT;
#pragma unroll
        for (int s = 0; s < KSEQ; ++s) {
            float sc[TT];
#pragma unroll
            for (int q = 0; q < 12; ++q) {
                float4 fv4 = *reinterpret_cast<const float4*>(&fvb[s][4 * q]);
                float4 te4 = *reinterpret_cast<const float4*>(te + 4 * q);
                sc[4 * q + 0] = fmaf(fv4.x, LN2, te4.x);
                sc[4 * q + 1] = fmaf(fv4.y, LN2, te4.y);
                sc[4 * q + 2] = fmaf(fv4.z, LN2, te4.z);
                sc[4 * q + 3] = fmaf(fv4.w, LN2, te4.w);
            }
            float m = sc[0];
#pragma unroll
            for (int j = 1; j < TT; ++j) m = fmaxf(m, sc[j]);
            float sum = 0.0f;
#pragma unroll
            for (int j = 0; j < TT; ++j) sum += __expf(sc[j] - m);
            if (lane == 0) out[b0 + s] = m + __logf(sum);
        }
    }
}

extern "C" void kernel_launch(void* const* d_in, const int* in_sizes, int n_in,
                              void* d_out, int out_size, void* d_ws, size_t ws_size,
                              hipStream_t stream) {
    (void)in_sizes; (void)n_in; (void)out_size; (void)d_ws; (void)ws_size;
    const float* feats = (const float*)d_in[0];   // [128, 512, 48] f32
    const float* trans = (const float*)d_in[1];   // [48, 48] f32
    float* out = (float*)d_out;                   // [128] f32
    crf_forward_kernel<<<dim3(NBLK), dim3(64), 0, stream>>>(feats, trans, out);
}

// Round 10
// 272.262 us; speedup vs baseline: 1.5082x; 1.5082x over previous
//
#include <hip/hip_runtime.h>
#include <math.h>

// CRF forward-score scan, faithful to the reference's quirky log_sum_exp.
// Base-2 factorization (HW-verified r5/r6/r8/r9, absmax 0.0):
//   M2_i   = max_j(fv2_j + tr2_ij)
//   h_j    = exp2(fv2_j - M2_j - feat2_j)
//   fv2'_i = M2_i + 2*feat2_i + log2(sum_j exp2(tr2_ij) * h_j)
//
// Measured ladder (cyc per block-step): r5 3-wave+barriers 832 | r6 KSEQ4
// 510/seq but 2038/block | r8 1-wave quad-split 975 | r9 KSEQ2 850/seq,
// 1700/block. LESSON: wall = 512 x block-step time; blocks are never
// resource-limited (128 blocks <= 256 CUs) -> KSEQ>1 can't win. This round
// shortens the single-seq chain itself: LANE-PER-ROW layout.
//   - lane i (0..47) owns row i: tr2 row + E row in 96 VGPRs.
//   - both per-row reductions (max_j, dot_j) are fully LANE-LOCAL: no DPP,
//     no quad exchange, 1 exp2 + 1 log2 per step (was 3 each).
//   - cross-lane traffic = two 48-float all-gathers per step, each:
//     1 masked ds_write_b32 + 12 broadcast ds_read_b128 (uniform address ->
//     conflict-free). Compiler's counted lgkmcnt overlaps the 12 reads with
//     the 48-wide add/max and FMA trees.
//   - single wave, zero barriers, in-order DS pipe gives write->read
//     visibility for free (r8-verified).
// Features via global_load_lds double-buffer (r8-verified), CHUNK=32,
// vmcnt(0) at sl==30 only.

#define TT 48
#define BB 128
#define SS 512
#define STARTI 46
#define ENDI 47
#define MINV 0.0001f
#define CHUNK 32
#define NCHUNK (SS / CHUNK)   // 16
#define GPT 6                 // gload16 per chunk: 32*48*4B / (64*16B)
#define LOG2E 1.44269504088896340736f
#define LN2   0.69314718055994530942f

#if __has_builtin(__builtin_amdgcn_exp2f)
#define EXP2F(x) __builtin_amdgcn_exp2f(x)
#else
#define EXP2F(x) exp2f(x)
#endif
#if __has_builtin(__builtin_amdgcn_logf)   // v_log_f32: log base 2
#define LOG2F(x) __builtin_amdgcn_logf(x)
#else
#define LOG2F(x) log2f(x)
#endif

#if __has_builtin(__builtin_amdgcn_global_load_lds)
#define HAVE_GLOAD 1
__device__ __forceinline__ void gload16(const float* g, float* l) {
    __builtin_amdgcn_global_load_lds(
        (const __attribute__((address_space(1))) void*)g,
        (__attribute__((address_space(3))) void*)l, 16, 0, 0);
}
#else
#define HAVE_GLOAD 0
#endif

__device__ __forceinline__ float m3(float a, float b, float c) {
    return fmaxf(fmaxf(a, b), c);   // clang fuses to v_max3_f32
}

__global__ __launch_bounds__(64, 1) void crf_forward_kernel(
    const float* __restrict__ feats,   // [B, S, T]
    const float* __restrict__ trans,   // [T, T]
    float* __restrict__ out)           // [B]
{
    const int lane = threadIdx.x;              // 0..63
    const int row  = (lane < TT) ? lane : TT - 1;   // lanes 48-63 shadow row 47
    const int b    = blockIdx.x;

    __shared__ __align__(16) float fvx[TT];
    __shared__ __align__(16) float hx[TT];
    __shared__ __align__(16) float featbuf[2][CHUNK * TT];   // 2 x 6 KB

    // Own row of trans (base-2) and its exp2 -- 96 VGPRs, loop-invariant.
    float tr2r[TT], Er[TT];
#pragma unroll
    for (int q = 0; q < 12; ++q) {
        float4 v = *reinterpret_cast<const float4*>(trans + row * TT + 4 * q);
        tr2r[4 * q + 0] = v.x * LOG2E; tr2r[4 * q + 1] = v.y * LOG2E;
        tr2r[4 * q + 2] = v.z * LOG2E; tr2r[4 * q + 3] = v.w * LOG2E;
    }
#pragma unroll
    for (int k = 0; k < TT; ++k) Er[k] = EXP2F(tr2r[k]);   // == exp(tr)

    const float* fb = feats + (size_t)b * SS * TT;

    // Preload chunk 0.
#if HAVE_GLOAD
#pragma unroll
    for (int k = 0; k < GPT; ++k)
        gload16(fb + k * 256 + lane * 4, &featbuf[0][k * 256]);
#else
#pragma unroll
    for (int k = 0; k < GPT; ++k)
        *reinterpret_cast<float4*>(&featbuf[0][k * 256 + lane * 4]) =
            *reinterpret_cast<const float4*>(fb + k * 256 + lane * 4);
#endif

    // fv2_0: MIN*log2e everywhere except 0 at START.
    if (lane < TT) fvx[lane] = (lane == STARTI) ? 0.0f : (MINV * LOG2E);
    float fv2i = (row == STARTI) ? 0.0f : (MINV * LOG2E);

#if HAVE_GLOAD
    asm volatile("s_waitcnt vmcnt(0)" ::: "memory");
#endif

    for (int c = 0; c < NCHUNK; ++c) {
        const int buf = c & 1;
        const bool hp = (c + 1 < NCHUNK);
        if (hp) {
#if HAVE_GLOAD
#pragma unroll
            for (int k = 0; k < GPT; ++k)
                gload16(fb + (c + 1) * (CHUNK * TT) + k * 256 + lane * 4,
                        &featbuf[buf ^ 1][k * 256]);
#else
#pragma unroll
            for (int k = 0; k < GPT; ++k)
                *reinterpret_cast<float4*>(&featbuf[buf ^ 1][k * 256 + lane * 4]) =
                    *reinterpret_cast<const float4*>(
                        fb + (c + 1) * (CHUNK * TT) + k * 256 + lane * 4);
#endif
        }

        for (int sl = 0; sl < CHUNK; ++sl) {
            // Own feat (stride-1 across lanes, 2-way bank alias = free).
            const float feat2 = featbuf[buf][sl * TT + row] * LOG2E;

            // ---- all-gather fv (12 broadcast b128 reads) + local max tree --
            float g[TT];
#pragma unroll
            for (int q = 0; q < 12; ++q) {
                float4 v = *reinterpret_cast<const float4*>(&fvx[4 * q]);
                g[4 * q + 0] = v.x; g[4 * q + 1] = v.y;
                g[4 * q + 2] = v.z; g[4 * q + 3] = v.w;
            }
            float a[TT];
#pragma unroll
            for (int k = 0; k < TT; ++k) a[k] = g[k] + tr2r[k];
            float t16[16];
#pragma unroll
            for (int u = 0; u < 16; ++u)
                t16[u] = m3(a[3 * u], a[3 * u + 1], a[3 * u + 2]);
            float t6_0 = m3(t16[0],  t16[1],  t16[2]);
            float t6_1 = m3(t16[3],  t16[4],  t16[5]);
            float t6_2 = m3(t16[6],  t16[7],  t16[8]);
            float t6_3 = m3(t16[9],  t16[10], t16[11]);
            float t6_4 = m3(t16[12], t16[13], t16[14]);
            float t6_5 = t16[15];
            const float M2 = fmaxf(m3(t6_0, t6_1, t6_2), m3(t6_3, t6_4, t6_5));

            const float h   = EXP2F((fv2i - feat2) - M2);
            const float qv2 = M2 + 2.0f * feat2;
            if (lane < TT) hx[lane] = h;

            // ---- all-gather h (12 broadcast b128 reads) + local dot -------
            float hg[TT];
#pragma unroll
            for (int q = 0; q < 12; ++q) {
                float4 v = *reinterpret_cast<const float4*>(&hx[4 * q]);
                hg[4 * q + 0] = v.x; hg[4 * q + 1] = v.y;
                hg[4 * q + 2] = v.z; hg[4 * q + 3] = v.w;
            }
            float acc[8];
#pragma unroll
            for (int u = 0; u < 8; ++u) acc[u] = Er[u] * hg[u];
#pragma unroll
            for (int k = 8; k < TT; ++k)
                acc[k & 7] = fmaf(Er[k], hg[k], acc[k & 7]);
            const float dot = ((acc[0] + acc[1]) + (acc[2] + acc[3]))
                            + ((acc[4] + acc[5]) + (acc[6] + acc[7]));

            const float nfv = qv2 + LOG2F(dot);
            fv2i = nfv;
            if (lane < TT) fvx[lane] = nfv;

#if HAVE_GLOAD
            if (sl == CHUNK - 2 && hp)
                asm volatile("s_waitcnt vmcnt(0)" ::: "memory");
#endif
        }
    }

    // ---- terminal: out[b] = LSE_j( fv_j + trans[END][j] ) ----
    // In-order DS: fvx writes above are visible to these reads (same wave).
    {
        const float* te = trans + ENDI * TT;
        float sc[TT];
#pragma unroll
        for (int q = 0; q < 12; ++q) {
            float4 fv4 = *reinterpret_cast<const float4*>(&fvx[4 * q]);
            float4 te4 = *reinterpret_cast<const float4*>(te + 4 * q);
            sc[4 * q + 0] = fmaf(fv4.x, LN2, te4.x);
            sc[4 * q + 1] = fmaf(fv4.y, LN2, te4.y);
            sc[4 * q + 2] = fmaf(fv4.z, LN2, te4.z);
            sc[4 * q + 3] = fmaf(fv4.w, LN2, te4.w);
        }
        float m = sc[0];
#pragma unroll
        for (int j = 1; j < TT; ++j) m = fmaxf(m, sc[j]);
        float s = 0.0f;
#pragma unroll
        for (int j = 0; j < TT; ++j) s += __expf(sc[j] - m);
        if (lane == 0) out[b] = m + __logf(s);
    }
}

extern "C" void kernel_launch(void* const* d_in, const int* in_sizes, int n_in,
                              void* d_out, int out_size, void* d_ws, size_t ws_size,
                              hipStream_t stream) {
    (void)in_sizes; (void)n_in; (void)out_size; (void)d_ws; (void)ws_size;
    const float* feats = (const float*)d_in[0];   // [128, 512, 48] f32
    const float* trans = (const float*)d_in[1];   // [48, 48] f32
    float* out = (float*)d_out;                   // [128] f32
    crf_forward_kernel<<<dim3(BB), dim3(64), 0, stream>>>(feats, trans, out);
}